// Round 1
// baseline (30247.437 us; speedup 1.0000x reference)
//
#include <hip/hip_runtime.h>
#include <stdint.h>
#include <stddef.h>

typedef _Float16 f16;
typedef _Float16 half2_t __attribute__((ext_vector_type(2)));
typedef _Float16 half8_t __attribute__((ext_vector_type(8)));
typedef float   float4_t __attribute__((ext_vector_type(4)));

#define T_STEPS 8192

// ---------------- workspace layout (bytes) ----------------
#define OFF_ZX   ((size_t)0)                    // Zx0  f16 [8192][4096]      = 67108864
#define OFF_WSW  ((size_t)67108864)             // WSW  u32 [256][256][96]    = 25165824
#define OFF_HS   (OFF_WSW + (size_t)25165824)   // hs   f16 [8192][1024]      = 16777216
#define OFF_H0R  (OFF_HS + (size_t)16777216)    // H0 ring f32 [4][1024]      = 16384
#define OFF_H1R  (OFF_H0R + (size_t)16384)      // H1 ring f32 [4][1024]      = 16384
#define OFF_CNT  (OFF_H1R + (size_t)16384)      // cnt u32 [8][8193]          = 262176
// total ~ 104.3 MiB

__device__ __forceinline__ uint32_t packh(float a, float b) {
  half2_t h; h.x = (_Float16)a; h.y = (_Float16)b;
  return __builtin_bit_cast(uint32_t, h);
}

__device__ __forceinline__ float fdot2w(uint32_t w, uint32_t h, float c) {
#if __has_builtin(__builtin_amdgcn_fdot2)
  return __builtin_amdgcn_fdot2(__builtin_bit_cast(half2_t, w),
                                __builtin_bit_cast(half2_t, h), c, false);
#else
  half2_t a = __builtin_bit_cast(half2_t, w);
  half2_t b = __builtin_bit_cast(half2_t, h);
  return c + (float)a.x * (float)b.x + (float)a.y * (float)b.y;
#endif
}

__device__ __forceinline__ float sigf(float x) { return 1.f / (1.f + __expf(-x)); }
__device__ __forceinline__ float tanhf_(float x) { return 2.f * sigf(2.f * x) - 1.f; }

// ---------------- init: zero sync counters and h rings ----------------
__global__ void k_init(uint32_t* __restrict__ cnt, float* __restrict__ H0R,
                       float* __restrict__ H1R) {
  int i = blockIdx.x * blockDim.x + threadIdx.x;
  int n = gridDim.x * blockDim.x;
  for (int k = i; k < 8 * (T_STEPS + 1); k += n) cnt[k] = 0u;
  for (int k = i; k < 4 * 1024; k += n) { H0R[k] = 0.f; H1R[k] = 0.f; }
}

// ---------------- pack recurrent weights into per-thread f16 pairs ----------------
// block b owns h0/h1 outputs 4b..4b+3. wave w = gate g. thread lane l covers
// column pairs (l+128p, l+128p+64), p=0..7. word idx: L0 rr*8+p, L1ih 32+, L1hh 64+.
__global__ void k_prep_w(const float* __restrict__ whh0, const float* __restrict__ wih1,
                         const float* __restrict__ whh1, uint32_t* __restrict__ WSW) {
  int b = blockIdx.x, tid = threadIdx.x;
  int w = tid >> 6, l = tid & 63;
  uint32_t* dst = WSW + ((size_t)b * 256 + tid) * 96;
#pragma unroll
  for (int rr = 0; rr < 4; ++rr) {
    size_t R = (size_t)(4 * b + rr + 1024 * w) * 1024;
#pragma unroll
    for (int p = 0; p < 8; ++p) {
      int c0 = l + 128 * p, c1 = l + 128 * p + 64;
      dst[rr * 8 + p]      = packh(whh0[R + c0], whh0[R + c1]);
      dst[32 + rr * 8 + p] = packh(wih1[R + c0], wih1[R + c1]);
      dst[64 + rr * 8 + p] = packh(whh1[R + c0], whh1[R + c1]);
    }
  }
}

// ---------------- generic 128x128 MFMA f16 GEMM: C[m][n] = A[m][:]·B[n][:] + bias(n) ----------------
// A: f32 or f16 [M][lda]; B: f32 [N][K] (row-major, i.e. B^T w.r.t. the product).
template <bool A16, bool OUT16>
__global__ __launch_bounds__(256) void k_gemm(const void* __restrict__ Ap,
                                              const float* __restrict__ B,
                                              const float* __restrict__ bias0,
                                              const float* __restrict__ bias1,
                                              void* __restrict__ Cp,
                                              int N, int K, int lda) {
  __shared__ __align__(16) f16 As[128 * 40];
  __shared__ __align__(16) f16 Bs[128 * 40];
  int bn = blockIdx.x * 128, bm = blockIdx.y * 128;
  int tid = threadIdx.x;
  int w = tid >> 6, l = tid & 63;
  int m0w = (w >> 1) * 64, n0w = (w & 1) * 64;
  int lr = l & 15, q = l >> 4;
  int srow = tid >> 1, skoff = (tid & 1) * 16;

  float4_t acc[4][4];
#pragma unroll
  for (int i = 0; i < 4; ++i)
#pragma unroll
    for (int j = 0; j < 4; ++j) acc[i][j] = (float4_t){0.f, 0.f, 0.f, 0.f};

  for (int kt = 0; kt < K; kt += 32) {
    __syncthreads();
    // stage A
    if (A16) {
      const f16* Ah = (const f16*)Ap + (size_t)(bm + srow) * lda + kt + skoff;
      uint4 u0 = *(const uint4*)Ah;
      uint4 u1 = *(const uint4*)(Ah + 8);
      *(uint4*)&As[srow * 40 + skoff] = u0;
      *(uint4*)&As[srow * 40 + skoff + 8] = u1;
    } else {
      const float* Af = (const float*)Ap + (size_t)(bm + srow) * lda + kt + skoff;
      const float4_t* A4 = (const float4_t*)Af;
      float4_t f0 = A4[0], f1 = A4[1], f2 = A4[2], f3 = A4[3];
      half8_t h0 = {(f16)f0.x, (f16)f0.y, (f16)f0.z, (f16)f0.w,
                    (f16)f1.x, (f16)f1.y, (f16)f1.z, (f16)f1.w};
      half8_t h1 = {(f16)f2.x, (f16)f2.y, (f16)f2.z, (f16)f2.w,
                    (f16)f3.x, (f16)f3.y, (f16)f3.z, (f16)f3.w};
      *(half8_t*)&As[srow * 40 + skoff] = h0;
      *(half8_t*)&As[srow * 40 + skoff + 8] = h1;
    }
    // stage B (always f32)
    {
      const float* Bf = B + (size_t)(bn + srow) * K + kt + skoff;
      const float4_t* B4 = (const float4_t*)Bf;
      float4_t f0 = B4[0], f1 = B4[1], f2 = B4[2], f3 = B4[3];
      half8_t h0 = {(f16)f0.x, (f16)f0.y, (f16)f0.z, (f16)f0.w,
                    (f16)f1.x, (f16)f1.y, (f16)f1.z, (f16)f1.w};
      half8_t h1 = {(f16)f2.x, (f16)f2.y, (f16)f2.z, (f16)f2.w,
                    (f16)f3.x, (f16)f3.y, (f16)f3.z, (f16)f3.w};
      *(half8_t*)&Bs[srow * 40 + skoff] = h0;
      *(half8_t*)&Bs[srow * 40 + skoff + 8] = h1;
    }
    __syncthreads();
    half8_t af[4], bf[4];
#pragma unroll
    for (int i = 0; i < 4; ++i) af[i] = *(const half8_t*)&As[(m0w + 16 * i + lr) * 40 + q * 8];
#pragma unroll
    for (int j = 0; j < 4; ++j) bf[j] = *(const half8_t*)&Bs[(n0w + 16 * j + lr) * 40 + q * 8];
#pragma unroll
    for (int i = 0; i < 4; ++i)
#pragma unroll
      for (int j = 0; j < 4; ++j)
        acc[i][j] = __builtin_amdgcn_mfma_f32_16x16x32_f16(af[i], bf[j], acc[i][j], 0, 0, 0);
  }

  // epilogue: C/D layout col = lane&15, row = (lane>>4)*4 + reg
#pragma unroll
  for (int j = 0; j < 4; ++j) {
    int n = bn + n0w + 16 * j + lr;
    float bv = bias0 ? bias0[n] : 0.f;
    if (bias1) bv += bias1[n];
#pragma unroll
    for (int i = 0; i < 4; ++i) {
#pragma unroll
      for (int r = 0; r < 4; ++r) {
        int m = bm + m0w + 16 * i + q * 4 + r;
        float v = acc[i][j][r] + bv;
        if (OUT16) ((f16*)Cp)[(size_t)m * N + n] = (f16)v;
        else       ((float*)Cp)[(size_t)m * N + n] = v;
      }
    }
  }
}

// ---------------- persistent serial LSTM kernel ----------------
// 256 blocks x 256 threads. Phase t computes layer0 step t and layer1 step t-1.
// One device-wide flag sync per phase through LLC (sc0/sc1 atomics).
__global__ __launch_bounds__(256, 1) void k_serial(
    const f16* __restrict__ Zx, const uint32_t* __restrict__ WSW,
    float* __restrict__ H0R, float* __restrict__ H1R, f16* __restrict__ hs,
    uint32_t* __restrict__ cnt, const float* __restrict__ b_ih1,
    const float* __restrict__ b_hh1) {
  __shared__ __align__(16) uint32_t h0L[512];
  __shared__ __align__(16) uint32_t h1L[512];
  __shared__ __align__(16) float red[48 * 20];
  __shared__ float zarr[48];

  int b = blockIdx.x, tid = threadIdx.x;
  int w = tid >> 6, l = tid & 63;

  // persistent per-thread weights: 96 dwords (f16x2)
  uint32_t wreg[96];
  {
    const uint4* src = (const uint4*)(WSW + ((size_t)b * 256 + tid) * 96);
#pragma unroll
    for (int q = 0; q < 24; ++q) {
      uint4 u = src[q];
      wreg[4 * q + 0] = u.x; wreg[4 * q + 1] = u.y;
      wreg[4 * q + 2] = u.z; wreg[4 * q + 3] = u.w;
    }
  }
  float c0 = 0.f, c1 = 0.f;
  float b1v[4] = {0.f, 0.f, 0.f, 0.f};
  if (tid >= 4 && tid < 8) {
    int j = tid - 4;
#pragma unroll
    for (int g = 0; g < 4; ++g) {
      int R = 4 * b + j + 1024 * g;
      b1v[g] = b_ih1[R] + b_hh1[R];
    }
  }
  const int cbase = (b & 7) * (T_STEPS + 1);

  for (int t = 0; t <= T_STEPS; ++t) {
    // ---- 1. wait for previous phase (8 striped counters, 32 blocks each) ----
    if (t > 0 && tid < 8) {
      const uint32_t* cp = &cnt[tid * (T_STEPS + 1) + (t - 1)];
      while (__hip_atomic_load(cp, __ATOMIC_RELAXED, __HIP_MEMORY_SCOPE_AGENT) < 32u) {}
    }
    __syncthreads();

    // ---- Zx prefetch for this block's 16 layer-0 gate rows ----
    float zxv = 0.f;
    if (t < T_STEPS && tid < 16) {
      int j = tid & 3, g = tid >> 2;
      zxv = (float)Zx[(size_t)t * 4096 + 4 * b + j + 1024 * g];
    }

    // ---- 2. stage h0_{t-1}, h1_{t-2} from LLC into LDS as f16 pairs ----
    {
      int slot = (t & 3) * 1024;
      int p = tid >> 5, l0 = (2 * tid) & 63;
      int e = l0 + 128 * p;
      unsigned long long a0 = __hip_atomic_load(
          (const unsigned long long*)(const void*)&H0R[slot + e],
          __ATOMIC_RELAXED, __HIP_MEMORY_SCOPE_AGENT);
      unsigned long long a1 = __hip_atomic_load(
          (const unsigned long long*)(const void*)&H0R[slot + e + 64],
          __ATOMIC_RELAXED, __HIP_MEMORY_SCOPE_AGENT);
      unsigned long long d0 = __hip_atomic_load(
          (const unsigned long long*)(const void*)&H1R[slot + e],
          __ATOMIC_RELAXED, __HIP_MEMORY_SCOPE_AGENT);
      unsigned long long d1 = __hip_atomic_load(
          (const unsigned long long*)(const void*)&H1R[slot + e + 64],
          __ATOMIC_RELAXED, __HIP_MEMORY_SCOPE_AGENT);
      float a0lo = __builtin_bit_cast(float, (uint32_t)(a0 & 0xffffffffull));
      float a0hi = __builtin_bit_cast(float, (uint32_t)(a0 >> 32));
      float a1lo = __builtin_bit_cast(float, (uint32_t)(a1 & 0xffffffffull));
      float a1hi = __builtin_bit_cast(float, (uint32_t)(a1 >> 32));
      float d0lo = __builtin_bit_cast(float, (uint32_t)(d0 & 0xffffffffull));
      float d0hi = __builtin_bit_cast(float, (uint32_t)(d0 >> 32));
      float d1lo = __builtin_bit_cast(float, (uint32_t)(d1 & 0xffffffffull));
      float d1hi = __builtin_bit_cast(float, (uint32_t)(d1 >> 32));
      h0L[64 * p + l0]     = packh(a0lo, a1lo);
      h0L[64 * p + l0 + 1] = packh(a0hi, a1hi);
      h1L[64 * p + l0]     = packh(d0lo, d1lo);
      h1L[64 * p + l0 + 1] = packh(d0hi, d1hi);
    }
    __syncthreads();

    // ---- 3. partial dot products (weights in VGPRs) ----
    uint32_t h0w[8], h1w[8];
#pragma unroll
    for (int p = 0; p < 8; ++p) { h0w[p] = h0L[64 * p + l]; h1w[p] = h1L[64 * p + l]; }
    float acc0[4], accA[4], accB[4];
#pragma unroll
    for (int rr = 0; rr < 4; ++rr) { acc0[rr] = 0.f; accA[rr] = 0.f; accB[rr] = 0.f; }
#pragma unroll
    for (int rr = 0; rr < 4; ++rr) {
#pragma unroll
      for (int p = 0; p < 8; ++p) {
        acc0[rr] = fdot2w(wreg[rr * 8 + p],      h0w[p], acc0[rr]);
        accA[rr] = fdot2w(wreg[32 + rr * 8 + p], h0w[p], accA[rr]);
        accB[rr] = fdot2w(wreg[64 + rr * 8 + p], h1w[p], accB[rr]);
      }
    }
    // butterfly fold lanes {l, l^1, l^2} -> 16 column-groups
#pragma unroll
    for (int rr = 0; rr < 4; ++rr) {
      acc0[rr] += __shfl_xor(acc0[rr], 1); acc0[rr] += __shfl_xor(acc0[rr], 2);
      accA[rr] += __shfl_xor(accA[rr], 1); accA[rr] += __shfl_xor(accA[rr], 2);
      accB[rr] += __shfl_xor(accB[rr], 1); accB[rr] += __shfl_xor(accB[rr], 2);
    }
    if ((l & 3) == 0) {
      int g = l >> 2;
#pragma unroll
      for (int rr = 0; rr < 4; ++rr) {
        red[(4 * w + rr) * 20 + g]        = acc0[rr];
        red[(16 + 4 * w + rr) * 20 + g]   = accA[rr];
        red[(32 + 4 * w + rr) * 20 + g]   = accB[rr];
      }
    }
    __syncthreads();

    // ---- 4. final reduce: 48 rows x 16 groups ----
    if (tid < 48) {
      const float4_t* rp = (const float4_t*)&red[tid * 20];
      float4_t s4 = rp[0];
      s4 += rp[1]; s4 += rp[2]; s4 += rp[3];
      float s = s4.x + s4.y + s4.z + s4.w;
      if (tid < 16) s += zxv;
      zarr[tid] = s;
    }
    __syncthreads();

    // ---- 5. gates (torch order i,f,g,o) ----
    if (tid < 4) {
      if (t < T_STEPS) {
        int j = tid;
        float zi = zarr[j], zf = zarr[4 + j], zg = zarr[8 + j], zo = zarr[12 + j];
        float ig = sigf(zi), fg = sigf(zf), gg = tanhf_(zg), og = sigf(zo);
        c0 = fg * c0 + ig * gg;
        float h0 = og * tanhf_(c0);
        __hip_atomic_store(&H0R[(((t + 1) & 3) * 1024) + 4 * b + j], h0,
                           __ATOMIC_RELAXED, __HIP_MEMORY_SCOPE_AGENT);
      }
    } else if (tid < 8) {
      if (t > 0) {
        int j = tid - 4;
        float zi = zarr[16 + j]      + zarr[32 + j]      + b1v[0];
        float zf = zarr[16 + 4 + j]  + zarr[32 + 4 + j]  + b1v[1];
        float zg = zarr[16 + 8 + j]  + zarr[32 + 8 + j]  + b1v[2];
        float zo = zarr[16 + 12 + j] + zarr[32 + 12 + j] + b1v[3];
        float ig = sigf(zi), fg = sigf(zf), gg = tanhf_(zg), og = sigf(zo);
        c1 = fg * c1 + ig * gg;
        float h1 = og * tanhf_(c1);
        __hip_atomic_store(&H1R[(((t + 1) & 3) * 1024) + 4 * b + j], h1,
                           __ATOMIC_RELAXED, __HIP_MEMORY_SCOPE_AGENT);
        hs[(size_t)(t - 1) * 1024 + 4 * b + j] = (f16)h1;
      }
    }

    // ---- 6. release + arrive ----
    __builtin_amdgcn_s_waitcnt(0);   // all this thread's stores at coherent point
    __syncthreads();
    if (tid == 0 && t < T_STEPS) {
      __hip_atomic_fetch_add(&cnt[cbase + t], 1u, __ATOMIC_RELAXED,
                             __HIP_MEMORY_SCOPE_AGENT);
    }
  }
}

// ---------------- value head: v[t] = hs[t]·w_val + b_val ----------------
__global__ void k_values(const f16* __restrict__ hs, const float* __restrict__ w_val,
                         const float* __restrict__ b_val, float* __restrict__ outv) {
  int t = blockIdx.x * 4 + (threadIdx.x >> 6);
  int l = threadIdx.x & 63;
  const f16* row = hs + (size_t)t * 1024 + l * 16;
  const float* wv = w_val + l * 16;
  float s = 0.f;
#pragma unroll
  for (int i = 0; i < 16; ++i) s += (float)row[i] * wv[i];
#pragma unroll
  for (int d = 1; d < 64; d <<= 1) s += __shfl_xor(s, d);
  if (l == 0) outv[t] = s + b_val[0];
}

// ---------------- softmax over 512 logits per row, in place ----------------
__global__ void k_softmax(float* __restrict__ out) {
  int t = blockIdx.x * 4 + (threadIdx.x >> 6);
  int l = threadIdx.x & 63;
  float* row = out + (size_t)t * 512;
  float v[8];
  float m = -1e30f;
#pragma unroll
  for (int i = 0; i < 8; ++i) { v[i] = row[l + 64 * i]; m = fmaxf(m, v[i]); }
#pragma unroll
  for (int d = 1; d < 64; d <<= 1) m = fmaxf(m, __shfl_xor(m, d));
  float s = 0.f;
#pragma unroll
  for (int i = 0; i < 8; ++i) { v[i] = __expf(v[i] - m); s += v[i]; }
#pragma unroll
  for (int d = 1; d < 64; d <<= 1) s += __shfl_xor(s, d);
  float inv = 1.f / s;
#pragma unroll
  for (int i = 0; i < 8; ++i) row[l + 64 * i] = v[i] * inv;
}

extern "C" void kernel_launch(void* const* d_in, const int* in_sizes, int n_in,
                              void* d_out, int out_size, void* d_ws, size_t ws_size,
                              hipStream_t stream) {
  const float* x      = (const float*)d_in[0];
  const float* w_ih0  = (const float*)d_in[1];
  const float* w_hh0  = (const float*)d_in[2];
  const float* b_ih0  = (const float*)d_in[3];
  const float* b_hh0  = (const float*)d_in[4];
  const float* w_ih1  = (const float*)d_in[5];
  const float* w_hh1  = (const float*)d_in[6];
  const float* b_ih1  = (const float*)d_in[7];
  const float* b_hh1  = (const float*)d_in[8];
  const float* w_pol  = (const float*)d_in[9];
  const float* b_pol  = (const float*)d_in[10];
  const float* w_val  = (const float*)d_in[11];
  const float* b_val  = (const float*)d_in[12];

  char* ws = (char*)d_ws;
  f16*      Zx  = (f16*)(ws + OFF_ZX);
  uint32_t* WSW = (uint32_t*)(ws + OFF_WSW);
  f16*      hs  = (f16*)(ws + OFF_HS);
  float*    H0R = (float*)(ws + OFF_H0R);
  float*    H1R = (float*)(ws + OFF_H1R);
  uint32_t* cnt = (uint32_t*)(ws + OFF_CNT);
  float*    out = (float*)d_out;

  k_init<<<64, 256, 0, stream>>>(cnt, H0R, H1R);
  k_prep_w<<<256, 256, 0, stream>>>(w_hh0, w_ih1, w_hh1, WSW);
  // Zx0 = x @ w_ih0^T + b_ih0 + b_hh0 : M=8192, N=4096, K=512
  k_gemm<false, true><<<dim3(32, 64), 256, 0, stream>>>(
      (const void*)x, w_ih0, b_ih0, b_hh0, (void*)Zx, 4096, 512, 512);
  k_serial<<<256, 256, 0, stream>>>(Zx, WSW, H0R, H1R, hs, cnt, b_ih1, b_hh1);
  // policy logits = hs @ w_pol^T + b_pol : M=8192, N=512, K=1024 -> d_out (f32)
  k_gemm<true, false><<<dim3(4, 64), 256, 0, stream>>>(
      (const void*)hs, w_pol, b_pol, nullptr, (void*)out, 512, 1024, 1024);
  k_values<<<2048, 256, 0, stream>>>(hs, w_val, b_val, out + (size_t)8192 * 512);
  k_softmax<<<2048, 256, 0, stream>>>(out);
}